// Round 2
// baseline (107.730 us; speedup 1.0000x reference)
//
#include <hip/hip_runtime.h>

typedef __attribute__((ext_vector_type(4))) float f32x4;
typedef __attribute__((ext_vector_type(8))) short bf16x8;
typedef __attribute__((ext_vector_type(4))) unsigned short u16x4;

#define NB 8
#define LLEN 512
#define DD 768
#define MW 12
#define HH 384
#define TT (NB * LLEN)      // 4096 tokens
#define SS (LLEN * MW)      // 6144 spans per batch
#define KP (3 * HH)         // 1152 packed-K (hi/lo 3-pass)

#define PACKH_BLOCKS ((TT * 192) / 256)   // 3072
#define PACKW_BLOCKS ((DD * 192) / 256)   // 576

// ---------- helpers ----------
__device__ __forceinline__ unsigned short f2bf(float x) {
  unsigned u = __builtin_bit_cast(unsigned, x);
  u += 0x7fff + ((u >> 16) & 1);              // RNE
  return (unsigned short)(u >> 16);
}
__device__ __forceinline__ float bf2f(unsigned short b) {
  return __builtin_bit_cast(float, (unsigned)b << 16);
}
__device__ __forceinline__ void gload_lds16(const void* g, void* l) {
  __builtin_amdgcn_global_load_lds(
      (const __attribute__((address_space(1))) unsigned int*)g,
      (__attribute__((address_space(3))) unsigned int*)l, 16, 0, 0);
}

// ---------- merged pack: h -> A'u,A'v ([hi|hi|lo]), W -> B'u,B'v ([hi|lo|hi]) ----------
__global__ __launch_bounds__(256) void prep_k(const float* __restrict__ h,
                                              const float* __restrict__ W,
                                              unsigned short* __restrict__ Au,
                                              unsigned short* __restrict__ Av,
                                              unsigned short* __restrict__ Bu,
                                              unsigned short* __restrict__ Bv) {
  int bid = blockIdx.x;
  if (bid < PACKH_BLOCKS) {
    int idx = bid * 256 + threadIdx.x;        // over TT*192 float4s
    int t = idx / 192;
    int k = (idx - t * 192) * 4;
    f32x4 f = *(const f32x4*)(h + (size_t)idx * 4);
    unsigned short* A = (k < HH) ? Au : Av;
    int kk = (k < HH) ? k : k - HH;
    u16x4 hi, lo;
#pragma unroll
    for (int j = 0; j < 4; ++j) {
      float x = f[j];
      unsigned short hb = f2bf(x);
      hi[j] = hb;
      lo[j] = f2bf(x - bf2f(hb));
    }
    unsigned short* base = A + (size_t)t * KP + kk;
    *(u16x4*)(base) = hi;
    *(u16x4*)(base + HH) = hi;
    *(u16x4*)(base + 2 * HH) = lo;
  } else {
    int idx = (bid - PACKH_BLOCKS) * 256 + threadIdx.x;  // over DD*192 float4s
    int e = idx / 192;
    int k = (idx - e * 192) * 4;
    f32x4 f = *(const f32x4*)(W + (size_t)idx * 4);
    unsigned short* Bm = (k < HH) ? Bu : Bv;
    int kk = (k < HH) ? k : k - HH;
    u16x4 hi, lo;
#pragma unroll
    for (int j = 0; j < 4; ++j) {
      float x = f[j];
      unsigned short hb = f2bf(x);
      hi[j] = hb;
      lo[j] = f2bf(x - bf2f(hb));
    }
    unsigned short* base = Bm + (size_t)e * KP + kk;
    *(u16x4*)(base) = hi;
    *(u16x4*)(base + HH) = lo;
    *(u16x4*)(base + 2 * HH) = hi;
  }
}

// ---------- sentinel projections: us[e]=ss@W[e,:384], vs[e]=es@W[e,384:] ----------
__global__ __launch_bounds__(64) void sent_k(const float* __restrict__ ss,
                                             const float* __restrict__ es,
                                             const float* __restrict__ W,
                                             float* __restrict__ us, float* __restrict__ vs) {
  int e = blockIdx.x;
  int lane = threadIdx.x;
  float a = 0.f, b = 0.f;
  const float* w = W + (size_t)e * DD;
  for (int j = lane; j < HH; j += 64) {
    a += ss[j] * w[j];
    b += es[j] * w[HH + j];
  }
#pragma unroll
  for (int off = 32; off > 0; off >>= 1) {
    a += __shfl_down(a, off);
    b += __shfl_down(b, off);
  }
  if (lane == 0) { us[e] = a; vs[e] = b; }
}

// ---------- bf16 GEMM: C[M=4096][N=768] = A'[M][K'] * B'^T[N][K'] ----------
// BM=64, BN=128 -> grid 64x6x2 = 768 blocks = 3/CU exactly (load-balanced)
__global__ __launch_bounds__(256) void gemm_k(const unsigned short* __restrict__ Au,
                                              const unsigned short* __restrict__ Bu,
                                              const unsigned short* __restrict__ Av,
                                              const unsigned short* __restrict__ Bv,
                                              float* __restrict__ Uo, float* __restrict__ Vo) {
  const unsigned short* A;
  const unsigned short* Bm;
  float* C;
  if (blockIdx.z == 0) { A = Au; Bm = Bu; C = Uo; }
  else                 { A = Av; Bm = Bv; C = Vo; }

  __shared__ unsigned short As[64 * 64];    // 8 KB
  __shared__ unsigned short Bs[128 * 64];   // 16 KB

  const int tid = threadIdx.x;
  const int lane = tid & 63;
  const int w = tid >> 6;
  const int wr = w >> 1, wc = w & 1;        // 2x2 waves -> each 32x64 of the 64x128 tile
  const int l16 = lane & 15, l4 = lane >> 4;
  const int row0 = blockIdx.x * 64;
  const int col0 = blockIdx.y * 128;

  f32x4 acc[2][4] = {};
  const char* Ab = (const char*)A;
  const char* Bb = (const char*)Bm;

  for (int k0 = 0; k0 < KP; k0 += 64) {
    // stage A 64x64 (8KB: 2 16B-loads/thread), B^T 128x64 (16KB: 4 loads/thread)
#pragma unroll
    for (int r = 0; r < 2; ++r) {
      int o = (r * 256 + tid) * 16;         // byte offset in 8 KB tile
      int row = o >> 7, colb = o & 127;     // 128 B per row
      gload_lds16(Ab + ((size_t)(row0 + row) * KP + k0) * 2 + colb, (char*)As + o);
    }
#pragma unroll
    for (int r = 0; r < 4; ++r) {
      int o = (r * 256 + tid) * 16;
      int row = o >> 7, colb = o & 127;
      gload_lds16(Bb + ((size_t)(col0 + row) * KP + k0) * 2 + colb, (char*)Bs + o);
    }
    __syncthreads();

    bf16x8 af[2][2], bfr[2][4];
#pragma unroll
    for (int ks = 0; ks < 2; ++ks)
#pragma unroll
      for (int m = 0; m < 2; ++m)
        af[ks][m] = *(const bf16x8*)&As[(wr * 32 + m * 16 + l16) * 64 + ks * 32 + l4 * 8];
#pragma unroll
    for (int ks = 0; ks < 2; ++ks)
#pragma unroll
      for (int n = 0; n < 4; ++n)
        bfr[ks][n] = *(const bf16x8*)&Bs[(wc * 64 + n * 16 + l16) * 64 + ks * 32 + l4 * 8];

#pragma unroll
    for (int m = 0; m < 2; ++m)
#pragma unroll
      for (int n = 0; n < 4; ++n) {
        acc[m][n] = __builtin_amdgcn_mfma_f32_16x16x32_bf16(af[0][m], bfr[0][n], acc[m][n], 0, 0, 0);
        acc[m][n] = __builtin_amdgcn_mfma_f32_16x16x32_bf16(af[1][m], bfr[1][n], acc[m][n], 0, 0, 0);
      }
    __syncthreads();
  }

  // epilogue: D row=(lane>>4)*4+reg, col=lane&15 (m89-verified)
#pragma unroll
  for (int m = 0; m < 2; ++m) {
    int grow = row0 + wr * 32 + m * 16 + l4 * 4;
#pragma unroll
    for (int n = 0; n < 4; ++n) {
      int gcol = col0 + wc * 64 + n * 16 + l16;
#pragma unroll
      for (int r = 0; r < 4; ++r)
        C[(size_t)(grow + r) * DD + gcol] = acc[m][n][r];
    }
  }
}

// ---------- assembly: one block per token, loops its 12 spans (reuse in L1/L2) ----------
__global__ __launch_bounds__(192) void assemble_k(const int* __restrict__ span,
                                                  const float* __restrict__ U,
                                                  const float* __restrict__ V,
                                                  const float* __restrict__ us,
                                                  const float* __restrict__ vs,
                                                  const float* __restrict__ bias,
                                                  float* __restrict__ out) {
  const int tk = blockIdx.x;                 // 0 .. TT-1
  const int b = tk >> 9;                     // /512
  const int l = tk & 511;
  const int t0 = b * LLEN;
  const int e4 = threadIdx.x;                // 0..191
  const f32x4* U4 = (const f32x4*)U;
  const f32x4* V4 = (const f32x4*)V;
  const f32x4 bb = ((const f32x4*)bias)[e4];
  const size_t sbase = ((size_t)b * SS + (size_t)l * MW) * 2;
  f32x4* out4 = (f32x4*)out + ((size_t)b * SS + (size_t)l * MW) * 192 + e4;

#pragma unroll 4
  for (int wdx = 0; wdx < MW; ++wdx) {
    const int start = span[sbase + 2 * wdx];
    const int end   = span[sbase + 2 * wdx + 1];
    f32x4 pe = U4[(size_t)(t0 + end) * 192 + e4];
    f32x4 pv = (end + 1 >= LLEN) ? ((const f32x4*)vs)[e4]
                                 : V4[(size_t)(t0 + end + 1) * 192 + e4];
    f32x4 mu = (start == 0) ? ((const f32x4*)us)[e4]
                            : U4[(size_t)(t0 + start - 1) * 192 + e4];
    f32x4 mv = V4[(size_t)(t0 + start) * 192 + e4];
    f32x4 r = pe + pv - mu - mv + bb;
#pragma unroll
    for (int j = 0; j < 4; ++j) r[j] = fmaxf(r[j], 0.f);
    __builtin_nontemporal_store(r, out4 + (size_t)wdx * 192);
  }
}

// ---------- naive fallback (only if ws too small) ----------
__global__ __launch_bounds__(256) void naive_k(const float* __restrict__ h,
                                               const int* __restrict__ span,
                                               const float* __restrict__ W,
                                               const float* __restrict__ bias,
                                               const float* __restrict__ ss,
                                               const float* __restrict__ es,
                                               float* __restrict__ out) {
  int bs = blockIdx.x;
  int b = bs / SS;
  int start = span[(size_t)bs * 2 + 0];
  int end   = span[(size_t)bs * 2 + 1];
  __shared__ float rep[DD];
  const float* hb = h + (size_t)b * LLEN * DD;
  for (int k = threadIdx.x; k < HH; k += blockDim.x) {
    float fs = (start == 0) ? ss[k] : hb[(size_t)(start - 1) * DD + k];
    rep[k] = hb[(size_t)end * DD + k] - fs;
    float bstart = (end + 1 >= LLEN) ? es[k] : hb[(size_t)(end + 1) * DD + HH + k];
    rep[HH + k] = bstart - hb[(size_t)start * DD + HH + k];
  }
  __syncthreads();
  for (int e = threadIdx.x; e < DD; e += blockDim.x) {
    const float* w = W + (size_t)e * DD;
    float acc = bias[e];
    for (int k = 0; k < DD; k += 4) {
      acc += rep[k] * w[k] + rep[k + 1] * w[k + 1] + rep[k + 2] * w[k + 2] + rep[k + 3] * w[k + 3];
    }
    out[(size_t)bs * DD + e] = fmaxf(acc, 0.f);
  }
}

extern "C" void kernel_launch(void* const* d_in, const int* in_sizes, int n_in,
                              void* d_out, int out_size, void* d_ws, size_t ws_size,
                              hipStream_t stream) {
  const float* h  = (const float*)d_in[0];
  const int* span = (const int*)d_in[1];
  const float* W  = (const float*)d_in[2];
  const float* bias = (const float*)d_in[3];
  const float* ss = (const float*)d_in[4];
  const float* es = (const float*)d_in[5];
  float* out = (float*)d_out;

  const size_t szU  = (size_t)TT * DD * sizeof(float);            // 12.58 MB
  const size_t szA  = (size_t)TT * KP * sizeof(unsigned short);   // 9.44 MB
  const size_t szB  = (size_t)DD * KP * sizeof(unsigned short);   // 1.77 MB
  const size_t szS  = DD * sizeof(float);
  const size_t need = 2 * szU + 2 * szA + 2 * szB + 2 * szS;      // ~47.6 MB

  if (ws_size < need) {
    naive_k<<<NB * SS, 256, 0, stream>>>(h, span, W, bias, ss, es, out);
    return;
  }

  char* ws = (char*)d_ws;
  float* U = (float*)ws;
  float* V = (float*)(ws + szU);
  unsigned short* Au = (unsigned short*)(ws + 2 * szU);
  unsigned short* Av = (unsigned short*)(ws + 2 * szU + szA);
  unsigned short* Bu = (unsigned short*)(ws + 2 * szU + 2 * szA);
  unsigned short* Bv = (unsigned short*)(ws + 2 * szU + 2 * szA + szB);
  float* us = (float*)(ws + 2 * szU + 2 * szA + 2 * szB);
  float* vs = us + DD;

  prep_k<<<PACKH_BLOCKS + PACKW_BLOCKS, 256, 0, stream>>>(h, W, Au, Av, Bu, Bv);
  sent_k<<<DD, 64, 0, stream>>>(ss, es, W, us, vs);
  gemm_k<<<dim3(TT / 64, DD / 128, 2), 256, 0, stream>>>(Au, Bu, Av, Bv, U, V);
  assemble_k<<<TT, 192, 0, stream>>>(span, U, V, us, vs, bias, out);
}

// Round 3
// 74.081 us; speedup vs baseline: 1.4542x; 1.4542x over previous
//
#include <hip/hip_runtime.h>

typedef __attribute__((ext_vector_type(4))) float f32x4;
typedef __attribute__((ext_vector_type(8))) short bf16x8;
typedef __attribute__((ext_vector_type(4))) unsigned short u16x4;

#define NB 8
#define LLEN 512
#define DD 768
#define MW 12
#define HH 384
#define TT (NB * LLEN)      // 4096 tokens
#define SS (LLEN * MW)      // 6144 spans per batch
#define KP (3 * HH)         // 1152 packed-K (hi/lo 3-pass)
#define MM (2 * TT)         // 8192 fused GEMM rows (U then V)

#define PACKH_BLOCKS ((TT * 192) / 256)   // 3072
#define PACKW_BLOCKS ((DD * 192) / 256)   // 576
#define SENT_BLOCKS (DD / 4)              // 192
#define PREP_BLOCKS (PACKH_BLOCKS + PACKW_BLOCKS + SENT_BLOCKS)

// ---------- helpers ----------
__device__ __forceinline__ unsigned short f2bf(float x) {
  unsigned u = __builtin_bit_cast(unsigned, x);
  u += 0x7fff + ((u >> 16) & 1);              // RNE
  return (unsigned short)(u >> 16);
}
__device__ __forceinline__ float bf2f(unsigned short b) {
  return __builtin_bit_cast(float, (unsigned)b << 16);
}
__device__ __forceinline__ void gload_lds16(const void* g, void* l) {
  __builtin_amdgcn_global_load_lds(
      (const __attribute__((address_space(1))) unsigned int*)g,
      (__attribute__((address_space(3))) unsigned int*)l, 16, 0, 0);
}

// ---------- prep: h -> A ([hi|hi|lo], fwd rows 0..TT-1, bwd rows TT..2TT-1),
//                  W -> Bu,Bv ([hi|lo|hi]), sentinels -> us,vs ----------
__global__ __launch_bounds__(256) void prep_k(const float* __restrict__ h,
                                              const float* __restrict__ W,
                                              const float* __restrict__ ss,
                                              const float* __restrict__ es,
                                              unsigned short* __restrict__ A,
                                              unsigned short* __restrict__ Bu,
                                              unsigned short* __restrict__ Bv,
                                              float* __restrict__ us,
                                              float* __restrict__ vs) {
  int bid = blockIdx.x;
  if (bid < PACKH_BLOCKS) {
    int idx = bid * 256 + threadIdx.x;        // over TT*192 float4s
    int t = idx / 192;
    int k = (idx - t * 192) * 4;
    f32x4 f = *(const f32x4*)(h + (size_t)idx * 4);
    int row = (k < HH) ? t : TT + t;          // fwd half -> U rows, bwd -> V rows
    int kk = (k < HH) ? k : k - HH;
    u16x4 hi, lo;
#pragma unroll
    for (int j = 0; j < 4; ++j) {
      float x = f[j];
      unsigned short hb = f2bf(x);
      hi[j] = hb;
      lo[j] = f2bf(x - bf2f(hb));
    }
    unsigned short* base = A + (size_t)row * KP + kk;
    *(u16x4*)(base) = hi;
    *(u16x4*)(base + HH) = hi;
    *(u16x4*)(base + 2 * HH) = lo;
  } else if (bid < PACKH_BLOCKS + PACKW_BLOCKS) {
    int idx = (bid - PACKH_BLOCKS) * 256 + threadIdx.x;  // over DD*192 float4s
    int e = idx / 192;
    int k = (idx - e * 192) * 4;
    f32x4 f = *(const f32x4*)(W + (size_t)idx * 4);
    unsigned short* Bm = (k < HH) ? Bu : Bv;
    int kk = (k < HH) ? k : k - HH;
    u16x4 hi, lo;
#pragma unroll
    for (int j = 0; j < 4; ++j) {
      float x = f[j];
      unsigned short hb = f2bf(x);
      hi[j] = hb;
      lo[j] = f2bf(x - bf2f(hb));
    }
    unsigned short* base = Bm + (size_t)e * KP + kk;
    *(u16x4*)(base) = hi;
    *(u16x4*)(base + HH) = lo;
    *(u16x4*)(base + 2 * HH) = hi;
  } else {
    // sentinel projections: 4 e-values per block, 64 lanes each
    int e = (bid - PACKH_BLOCKS - PACKW_BLOCKS) * 4 + (threadIdx.x >> 6);
    int lane = threadIdx.x & 63;
    float a = 0.f, b = 0.f;
    const float* w = W + (size_t)e * DD;
    for (int j = lane; j < HH; j += 64) {
      a += ss[j] * w[j];
      b += es[j] * w[HH + j];
    }
#pragma unroll
    for (int off = 32; off > 0; off >>= 1) {
      a += __shfl_down(a, off);
      b += __shfl_down(b, off);
    }
    if (lane == 0) { us[e] = a; vs[e] = b; }
  }
}

// ---------- fused bf16 GEMM: C[M=8192][N=768] = A[M][KP] * B^T[N][KP] ----------
// BM=128, BN=96 -> grid 64x8 = 512 blocks = exactly 2/CU.
// Rows < TT use Bu (U output); rows >= TT use Bv (V output). C = U base, V = U + TT*DD.
__global__ __launch_bounds__(256) void gemm_k(const unsigned short* __restrict__ A,
                                              const unsigned short* __restrict__ Bu,
                                              const unsigned short* __restrict__ Bv,
                                              float* __restrict__ C) {
  __shared__ unsigned short As[128 * 64];   // 16 KB
  __shared__ unsigned short Bs[96 * 64];    // 12 KB

  const int tid = threadIdx.x;
  const int lane = tid & 63;
  const int w = tid >> 6;
  const int wr = w >> 1, wc = w & 1;        // 2x2 waves -> each 64x48
  const int l16 = lane & 15, l4 = lane >> 4;
  const int row0 = blockIdx.x * 128;
  const int col0 = blockIdx.y * 96;
  const unsigned short* Bm = (row0 < TT) ? Bu : Bv;

  f32x4 acc[4][3] = {};
  const char* Ab = (const char*)A;
  const char* Bb = (const char*)Bm;

  for (int k0 = 0; k0 < KP; k0 += 64) {
    // stage A 128x64 (16KB: 4 16B-loads/thread), B^T 96x64 (12KB: 3 loads/thread)
#pragma unroll
    for (int r = 0; r < 4; ++r) {
      int o = (r * 256 + tid) * 16;         // byte offset; 128 B per LDS row
      int row = o >> 7, colb = o & 127;
      gload_lds16(Ab + ((size_t)(row0 + row) * KP + k0) * 2 + colb, (char*)As + o);
    }
#pragma unroll
    for (int r = 0; r < 3; ++r) {
      int o = (r * 256 + tid) * 16;
      int row = o >> 7, colb = o & 127;
      gload_lds16(Bb + ((size_t)(col0 + row) * KP + k0) * 2 + colb, (char*)Bs + o);
    }
    __syncthreads();

    bf16x8 af[2][4], bfr[2][3];
#pragma unroll
    for (int ks = 0; ks < 2; ++ks)
#pragma unroll
      for (int m = 0; m < 4; ++m)
        af[ks][m] = *(const bf16x8*)&As[(wr * 64 + m * 16 + l16) * 64 + ks * 32 + l4 * 8];
#pragma unroll
    for (int ks = 0; ks < 2; ++ks)
#pragma unroll
      for (int n = 0; n < 3; ++n)
        bfr[ks][n] = *(const bf16x8*)&Bs[(wc * 48 + n * 16 + l16) * 64 + ks * 32 + l4 * 8];

#pragma unroll
    for (int m = 0; m < 4; ++m)
#pragma unroll
      for (int n = 0; n < 3; ++n) {
        acc[m][n] = __builtin_amdgcn_mfma_f32_16x16x32_bf16(af[0][m], bfr[0][n], acc[m][n], 0, 0, 0);
        acc[m][n] = __builtin_amdgcn_mfma_f32_16x16x32_bf16(af[1][m], bfr[1][n], acc[m][n], 0, 0, 0);
      }
    __syncthreads();
  }

  // epilogue: D row=(lane>>4)*4+reg, col=lane&15 (m89-verified)
#pragma unroll
  for (int m = 0; m < 4; ++m) {
    int grow = row0 + wr * 64 + m * 16 + l4 * 4;
#pragma unroll
    for (int n = 0; n < 3; ++n) {
      int gcol = col0 + wc * 48 + n * 16 + l16;
#pragma unroll
      for (int r = 0; r < 4; ++r)
        C[(size_t)(grow + r) * DD + gcol] = acc[m][n][r];
    }
  }
}

// ---------- assembly: one block per token (XCD-swizzled), loops its 12 spans ----------
__global__ __launch_bounds__(192) void assemble_k(const int* __restrict__ span,
                                                  const float* __restrict__ U,
                                                  const float* __restrict__ V,
                                                  const float* __restrict__ us,
                                                  const float* __restrict__ vs,
                                                  const float* __restrict__ bias,
                                                  float* __restrict__ out) {
  // XCD swizzle: blocks round-robin across 8 XCDs -> give XCD x tokens [x*512,(x+1)*512)
  // so each XCD's U/V working set (~3.1 MB) stays L2-resident.
  const int bid = blockIdx.x;
  const int tk = (bid & 7) * (TT / 8) + (bid >> 3);
  const int b = tk >> 9;                     // /512
  const int l = tk & 511;
  const int t0 = b * LLEN;
  const int e4 = threadIdx.x;                // 0..191
  const f32x4* U4 = (const f32x4*)U;
  const f32x4* V4 = (const f32x4*)V;
  const f32x4 bb = ((const f32x4*)bias)[e4];
  const size_t sbase = ((size_t)b * SS + (size_t)l * MW) * 2;
  f32x4* out4 = (f32x4*)out + ((size_t)b * SS + (size_t)l * MW) * 192 + e4;

#pragma unroll 4
  for (int wdx = 0; wdx < MW; ++wdx) {
    const int start = span[sbase + 2 * wdx];
    const int end   = span[sbase + 2 * wdx + 1];
    f32x4 pe = U4[(size_t)(t0 + end) * 192 + e4];
    f32x4 pv = (end + 1 >= LLEN) ? ((const f32x4*)vs)[e4]
                                 : V4[(size_t)(t0 + end + 1) * 192 + e4];
    f32x4 mu = (start == 0) ? ((const f32x4*)us)[e4]
                            : U4[(size_t)(t0 + start - 1) * 192 + e4];
    f32x4 mv = V4[(size_t)(t0 + start) * 192 + e4];
    f32x4 r = pe + pv - mu - mv + bb;
#pragma unroll
    for (int j = 0; j < 4; ++j) r[j] = fmaxf(r[j], 0.f);
    out4[(size_t)wdx * 192] = r;
  }
}

// ---------- naive fallback (only if ws too small) ----------
__global__ __launch_bounds__(256) void naive_k(const float* __restrict__ h,
                                               const int* __restrict__ span,
                                               const float* __restrict__ W,
                                               const float* __restrict__ bias,
                                               const float* __restrict__ ss,
                                               const float* __restrict__ es,
                                               float* __restrict__ out) {
  int bs = blockIdx.x;
  int b = bs / SS;
  int start = span[(size_t)bs * 2 + 0];
  int end   = span[(size_t)bs * 2 + 1];
  __shared__ float rep[DD];
  const float* hb = h + (size_t)b * LLEN * DD;
  for (int k = threadIdx.x; k < HH; k += blockDim.x) {
    float fs = (start == 0) ? ss[k] : hb[(size_t)(start - 1) * DD + k];
    rep[k] = hb[(size_t)end * DD + k] - fs;
    float bstart = (end + 1 >= LLEN) ? es[k] : hb[(size_t)(end + 1) * DD + HH + k];
    rep[HH + k] = bstart - hb[(size_t)start * DD + HH + k];
  }
  __syncthreads();
  for (int e = threadIdx.x; e < DD; e += blockDim.x) {
    const float* w = W + (size_t)e * DD;
    float acc = bias[e];
    for (int k = 0; k < DD; k += 4) {
      acc += rep[k] * w[k] + rep[k + 1] * w[k + 1] + rep[k + 2] * w[k + 2] + rep[k + 3] * w[k + 3];
    }
    out[(size_t)bs * DD + e] = fmaxf(acc, 0.f);
  }
}

extern "C" void kernel_launch(void* const* d_in, const int* in_sizes, int n_in,
                              void* d_out, int out_size, void* d_ws, size_t ws_size,
                              hipStream_t stream) {
  const float* h  = (const float*)d_in[0];
  const int* span = (const int*)d_in[1];
  const float* W  = (const float*)d_in[2];
  const float* bias = (const float*)d_in[3];
  const float* ss = (const float*)d_in[4];
  const float* es = (const float*)d_in[5];
  float* out = (float*)d_out;

  const size_t szU  = (size_t)TT * DD * sizeof(float);            // 12.58 MB
  const size_t szA  = (size_t)MM * KP * sizeof(unsigned short);   // 18.87 MB
  const size_t szB  = (size_t)DD * KP * sizeof(unsigned short);   // 1.77 MB
  const size_t szS  = DD * sizeof(float);
  const size_t need = 2 * szU + szA + 2 * szB + 2 * szS;          // ~47.6 MB

  if (ws_size < need) {
    naive_k<<<NB * SS, 256, 0, stream>>>(h, span, W, bias, ss, es, out);
    return;
  }

  char* ws = (char*)d_ws;
  float* U = (float*)ws;                                   // [TT][DD]
  float* V = U + (size_t)TT * DD;                          // [TT][DD] (GEMM rows TT..2TT-1)
  unsigned short* A  = (unsigned short*)(ws + 2 * szU);    // [MM][KP]
  unsigned short* Bu = (unsigned short*)(ws + 2 * szU + szA);
  unsigned short* Bv = (unsigned short*)(ws + 2 * szU + szA + szB);
  float* us = (float*)(ws + 2 * szU + szA + 2 * szB);
  float* vs = us + DD;

  prep_k<<<PREP_BLOCKS, 256, 0, stream>>>(h, W, ss, es, A, Bu, Bv, us, vs);
  gemm_k<<<dim3(MM / 128, DD / 96), 256, 0, stream>>>(A, Bu, Bv, U);
  assemble_k<<<TT, 192, 0, stream>>>(span, U, V, us, vs, bias, out);
}